// Round 1
// baseline (293.041 us; speedup 1.0000x reference)
//
#include <hip/hip_runtime.h>

// Problem constants (fixed by reference).
#define TT   512
#define BB   2048
#define DIN  8
#define NTAG 16

// ---------- cross-lane helpers ----------
__device__ __forceinline__ float dpp_xor1(float v) {
    int i = __builtin_bit_cast(int, v);
    int r = __builtin_amdgcn_update_dpp(0, i, 0xB1, 0xF, 0xF, true); // quad_perm [1,0,3,2]
    return __builtin_bit_cast(float, r);
}
__device__ __forceinline__ float dpp_xor2(float v) {
    int i = __builtin_bit_cast(int, v);
    int r = __builtin_amdgcn_update_dpp(0, i, 0x4E, 0xF, 0xF, true); // quad_perm [2,3,0,1]
    return __builtin_bit_cast(float, r);
}
__device__ __forceinline__ float bperm(int byte_addr, float v) {
    int r = __builtin_amdgcn_ds_bpermute(byte_addr, __builtin_bit_cast(int, v));
    return __builtin_bit_cast(float, r);
}

// ---------- recurrent scan ----------
// 64 threads/block = 1 wave = 4 batch elems. lane = e*16 + g*4 + k.
// Each lane owns (gate g, wire k) of elem e; redundantly tracks c_k, h_k.
__global__ __launch_bounds__(64) void qlstm_rec(
    const float* __restrict__ x,        // (T,B,8)
    const float* __restrict__ w_gates,  // (4,4,12)
    const float* __restrict__ b_gates,  // (4,4)
    const float* __restrict__ rx_theta, // (4,4)
    float* __restrict__ hbuf)           // (T,B,4)
{
    const int lane = threadIdx.x;
    const int e    = lane >> 4;
    const int g    = (lane >> 2) & 3;
    const int k    = lane & 3;
    const int b    = blockIdx.x * 4 + e;

    // Per-lane weights. h-weights preloaded in xor-gather order.
    const float* wrow = w_gates + (g * 4 + k) * 12;
    const float wx0 = wrow[0], wx1 = wrow[1], wx2 = wrow[2], wx3 = wrow[3];
    const float wx4 = wrow[4], wx5 = wrow[5], wx6 = wrow[6], wx7 = wrow[7];
    const float wh0 = wrow[8 + (k ^ 0)];
    const float wh1 = wrow[8 + (k ^ 1)];
    const float wh2 = wrow[8 + (k ^ 2)];
    const float wh3 = wrow[8 + (k ^ 3)];
    const float bias = b_gates[g * 4 + k] + rx_theta[g * 4 + k]; // fold RX theta into angle

    // bpermute byte addresses: act of gate j at this (e,k).
    const int base16 = lane & 48;
    const int a0 = (base16 | 0  | k) * 4;
    const int a1 = (base16 | 4  | k) * 4;
    const int a2 = (base16 | 8  | k) * 4;
    const int a3 = (base16 | 12 | k) * 4;

    const float L2E = 1.44269504088896f;
    // Branchless activation: gate 2 -> tanh, else sigmoid.
    //   eq = exp2(q*s); r = 1/(1+eq); act = r*aA + bA
    const float sA = (g == 2) ? (2.0f * L2E) : (-L2E);
    const float aA = (g == 2) ? -2.0f : 1.0f;
    const float bA = (g == 2) ?  1.0f : 0.0f;

    float h = 0.0f, c = 0.0f;
    const float* xb = x + (size_t)b * DIN;
    float* hout = hbuf + (size_t)b * 4 + k;

    float4 xc0 = *(const float4*)(xb);
    float4 xc1 = *(const float4*)(xb + 4);

    #pragma unroll 1
    for (int t = 0; t < TT; ++t) {
        // prefetch x for t+1 (independent of the h chain)
        const int tn = (t + 1 < TT) ? (t + 1) : t;
        const float4 xn0 = *(const float4*)(xb + (size_t)tn * (BB * DIN));
        const float4 xn1 = *(const float4*)(xb + (size_t)tn * (BB * DIN) + 4);

        // gather h[0..3] across wire-quad (xor order matches wh preload)
        const float h1 = dpp_xor1(h);
        const float h2 = dpp_xor2(h);
        const float h3 = dpp_xor1(h2);

        const float accx = bias
            + xc0.x * wx0 + xc0.y * wx1 + xc0.z * wx2 + xc0.w * wx3
            + xc1.x * wx4 + xc1.y * wx5 + xc1.z * wx6 + xc1.w * wx7;
        const float ang = accx + h * wh0 + h1 * wh1 + h2 * wh2 + h3 * wh3;

        const float C = __cosf(ang);
        // qout products via pair-product butterfly:
        //   k=0: C1*C2*C3, k=1: C0*C1, k=2: C0*C1*C2, k=3: C0*C1*C2*C3
        const float cx1  = dpp_xor1(C);
        const float pp   = C * cx1;        // {C0C1,C0C1,C2C3,C2C3}
        const float ppx2 = dpp_xor2(pp);   // {C2C3,C2C3,C0C1,C0C1}
        const float Asel = (k == 0) ? cx1 : ((k == 2) ? C : pp);
        const float Bsel = (k == 1) ? 1.0f : ppx2;
        const float q = Asel * Bsel;

        // activation
        const float eq  = exp2f(q * sA);
        const float r   = __builtin_amdgcn_rcpf(1.0f + eq);
        const float act = fmaf(r, aA, bA);

        // gather f,i,g~,o (gate-ordered) for this wire
        const float vf = bperm(a0, act);
        const float vi = bperm(a1, act);
        const float vg = bperm(a2, act);
        const float vo = bperm(a3, act);

        c = fmaf(vf, c, vi * vg);
        const float e2 = exp2f(c * (2.0f * L2E));
        const float tc = fmaf(__builtin_amdgcn_rcpf(1.0f + e2), -2.0f, 1.0f); // tanh(c)
        h = vo * tc;

        if (g == 0) hout[(size_t)t * (BB * 4)] = h;

        xc0 = xn0; xc1 = xn1;
    }
}

// ---------- projection + log_softmax ----------
__global__ __launch_bounds__(256) void qlstm_proj(
    const float* __restrict__ hbuf,   // (T*B, 4)
    const float* __restrict__ w_tag,  // (16,4)
    const float* __restrict__ b_tag,  // (16,)
    float* __restrict__ out)          // (T*B, 16)
{
    const int tb = blockIdx.x * 256 + threadIdx.x;
    const float4 h4 = *(const float4*)(hbuf + (size_t)tb * 4);

    float lg[NTAG];
    #pragma unroll
    for (int j = 0; j < NTAG; ++j) {
        const float* wr = w_tag + j * 4;
        lg[j] = b_tag[j] + h4.x * wr[0] + h4.y * wr[1] + h4.z * wr[2] + h4.w * wr[3];
    }
    float m = lg[0];
    #pragma unroll
    for (int j = 1; j < NTAG; ++j) m = fmaxf(m, lg[j]);
    const float L2E = 1.44269504088896f;
    float s = 0.0f;
    #pragma unroll
    for (int j = 0; j < NTAG; ++j) s += exp2f((lg[j] - m) * L2E);
    const float lse = m + log2f(s) * 0.69314718056f;

    float* o = out + (size_t)tb * NTAG;
    #pragma unroll
    for (int j = 0; j < NTAG; j += 4) {
        float4 v = { lg[j] - lse, lg[j+1] - lse, lg[j+2] - lse, lg[j+3] - lse };
        *(float4*)(o + j) = v;
    }
}

extern "C" void kernel_launch(void* const* d_in, const int* in_sizes, int n_in,
                              void* d_out, int out_size, void* d_ws, size_t ws_size,
                              hipStream_t stream) {
    const float* x        = (const float*)d_in[0];
    const float* w_gates  = (const float*)d_in[1];
    const float* b_gates  = (const float*)d_in[2];
    const float* rx_theta = (const float*)d_in[3];
    const float* w_tag    = (const float*)d_in[4];
    const float* b_tag    = (const float*)d_in[5];
    float* out  = (float*)d_out;
    float* hbuf = (float*)d_ws;   // needs T*B*4 floats = 16.8 MB

    qlstm_rec<<<BB / 4, 64, 0, stream>>>(x, w_gates, b_gates, rx_theta, hbuf);
    qlstm_proj<<<(TT * BB) / 256, 256, 0, stream>>>(hbuf, w_tag, b_tag, out);
}

// Round 2
// 210.687 us; speedup vs baseline: 1.3909x; 1.3909x over previous
//
#include <hip/hip_runtime.h>

// Problem constants (fixed by reference).
#define TT   512
#define BB   2048
#define NTAG 16
#define CH   8              // timesteps staged per chunk
#define NCH  (TT / CH)      // 64 chunks

// ---------- DPP helpers ----------
// row_ror:n on gfx9/CDNA: dst lane i <- src lane ((i-n) & 15) within its row of 16
// (rocPRIM/LLVM DPP-scan convention: row_shr:n pulls from lane i-n).
#define DPP_XOR1  0xB1    // quad_perm [1,0,3,2]  : lane ^ 1
#define DPP_XOR2  0x4E    // quad_perm [2,3,0,1]  : lane ^ 2
#define DPP_ROR4  0x124   // gate g+3 (lane i-4)
#define DPP_ROR8  0x128   // gate g+2
#define DPP_ROR12 0x12C   // gate g+1

template<int CTRL>
__device__ __forceinline__ float dppf(float v) {
    int r = __builtin_amdgcn_update_dpp(0, __builtin_bit_cast(int, v),
                                        CTRL, 0xF, 0xF, true);
    return __builtin_bit_cast(float, r);
}

// One fused kernel: recurrent scan + tag projection + log_softmax.
// 64 threads/block = 1 wave = 4 batch elems; lane = e*16 + g*4 + k.
__global__ __launch_bounds__(64) void qlstm_fused(
    const float* __restrict__ x,        // (T,B,8)
    const float* __restrict__ w_gates,  // (4,4,12)
    const float* __restrict__ b_gates,  // (4,4)
    const float* __restrict__ rx_theta, // (4,4)
    const float* __restrict__ w_tag,    // (16,4)
    const float* __restrict__ b_tag,    // (16,)
    float* __restrict__ out)            // (T,B,16)
{
    __shared__ float4 lds4[2][CH][8];   // [buf][step][4 elems * 32B]

    const int l = threadIdx.x;
    const int e = l >> 4;
    const int g = (l >> 2) & 3;
    const int k = l & 3;
    const int b0 = blockIdx.x * 4;

    // Per-lane gate weights; h-weights (and tag-weights) preloaded in xor-gather order.
    const float* wrow = w_gates + (g * 4 + k) * 12;
    const float wx0 = wrow[0], wx1 = wrow[1], wx2 = wrow[2], wx3 = wrow[3];
    const float wx4 = wrow[4], wx5 = wrow[5], wx6 = wrow[6], wx7 = wrow[7];
    const float wh0 = wrow[8 + (k ^ 0)];
    const float wh1 = wrow[8 + (k ^ 1)];
    const float wh2 = wrow[8 + (k ^ 2)];
    const float wh3 = wrow[8 + (k ^ 3)];
    const float bias = b_gates[g * 4 + k] + rx_theta[g * 4 + k];

    const int tag = g * 4 + k;          // this lane owns one output tag
    const float wt0 = w_tag[tag * 4 + (k ^ 0)];
    const float wt1 = w_tag[tag * 4 + (k ^ 1)];
    const float wt2 = w_tag[tag * 4 + (k ^ 2)];
    const float wt3 = w_tag[tag * 4 + (k ^ 3)];
    const float bt  = b_tag[tag];

    const float L2E = 1.44269504088896f;
    // Branchless activation: gate 2 -> tanh, else sigmoid.
    const float sA = (g == 2) ? (2.0f * L2E) : (-L2E);
    const float aA = (g == 2) ? -2.0f : 1.0f;
    const float bA = (g == 2) ?  1.0f : 0.0f;
    const bool k0 = (k == 0), k1 = (k == 1), k2 = (k == 2);
    const bool g0 = (g == 0), g1 = (g == 1), g2 = (g == 2);

    // x staging: lane covers step (l>>3) of each chunk, 16B slot (l&7).
    const float* xlane = x + (size_t)(l >> 3) * (BB * 8)
                           + (size_t)b0 * 8 + (l & 7) * 4;
    const size_t CHOFF = (size_t)CH * BB * 8;    // floats per chunk
    float4* ldsflat = (float4*)lds4;

    // ---- prologue: chunk0 -> buf0, chunk1 -> regs ----
    float4 reg = *(const float4*)(xlane);
    ldsflat[l] = reg;
    reg = *(const float4*)(xlane + CHOFF);

    float4 xcA = lds4[0][0][2 * e];
    float4 xcB = lds4[0][0][2 * e + 1];

    float h = 0.f, c = 0.f, h1 = 0.f, h2 = 0.f, h3 = 0.f;
    float* outp = out + (size_t)b0 * NTAG + l;   // 64 lanes = 256B contiguous per t

    for (int cc = 0; cc < NCH; ++cc) {
        const int cur = cc & 1;
        ldsflat[(cur ^ 1) * 64 + l] = reg;       // stage chunk cc+1
        const int cn = (cc + 2 < NCH) ? cc + 2 : NCH - 1;
        reg = *(const float4*)(xlane + (size_t)cn * CHOFF);  // issue chunk cc+2

        #pragma unroll
        for (int i = 0; i < CH; ++i) {
            const int t = cc * CH + i;
            // prefetch x for t+1 (off-chain; last iter reads next buffer)
            const int nb = (i == CH - 1) ? (cur ^ 1) : cur;
            const int ns = (i + 1) & (CH - 1);
            const float4 xnA = lds4[nb][ns][2 * e];
            const float4 xnB = lds4[nb][ns][2 * e + 1];

            const float accx = bias
                + xcA.x * wx0 + xcA.y * wx1 + xcA.z * wx2 + xcA.w * wx3
                + xcB.x * wx4 + xcB.y * wx5 + xcB.z * wx6 + xcB.w * wx7;
            const float p01 = fmaf(h,  wh0, h1 * wh1);
            const float p23 = fmaf(h2, wh2, h3 * wh3);
            const float ang = (accx + p01) + p23;

            const float C   = __cosf(ang);
            // wire-product butterfly: k0:C1C2C3, k1:C0C1, k2:C0C1C2, k3:C0C1C2C3
            const float cx1  = dppf<DPP_XOR1>(C);
            const float pp   = C * cx1;
            const float ppx2 = dppf<DPP_XOR2>(pp);
            const float Asel = k0 ? cx1 : (k2 ? C : pp);
            const float Bsel = k1 ? 1.0f : ppx2;
            const float q = Asel * Bsel;

            const float eq  = exp2f(q * sA);
            const float r   = __builtin_amdgcn_rcpf(1.0f + eq);
            const float act = fmaf(r, aA, bA);

            // gate gather via DPP rotations (no LDS round trip)
            const float rA = dppf<DPP_ROR12>(act);  // gate g+1
            const float rB = dppf<DPP_ROR8>(act);   // gate g+2
            const float rC = dppf<DPP_ROR4>(act);   // gate g+3
            const float vf = g0 ? act : (g1 ? rC : (g2 ? rB : rA));
            const float vi = g0 ? rA  : (g1 ? act : (g2 ? rC : rB));
            const float vg = g0 ? rB  : (g1 ? rA  : (g2 ? act : rC));
            const float vo = g0 ? rC  : (g1 ? rB  : (g2 ? rA  : act));

            c = fmaf(vf, c, vi * vg);
            const float e2c = exp2f(c * (2.0f * L2E));
            const float tc  = fmaf(__builtin_amdgcn_rcpf(1.0f + e2c), -2.0f, 1.0f);
            h = vo * tc;

            // h gather: feeds next step's h-dot AND this step's logits
            h1 = dppf<DPP_XOR1>(h);
            h2 = dppf<DPP_XOR2>(h);
            h3 = dppf<DPP_XOR1>(h2);

            // ---- fused projection + log_softmax (off the recurrence chain) ----
            const float lgq = fmaf(h, wt0, fmaf(h1, wt1, fmaf(h2, wt2,
                                 fmaf(h3, wt3, bt))));
            float m = fmaxf(lgq, dppf<DPP_XOR1>(lgq));
            m = fmaxf(m, dppf<DPP_XOR2>(m));
            m = fmaxf(m, dppf<DPP_ROR4>(m));
            m = fmaxf(m, dppf<DPP_ROR8>(m));
            const float ex = exp2f((lgq - m) * L2E);
            float s = ex + dppf<DPP_XOR1>(ex);
            s = s + dppf<DPP_XOR2>(s);
            s = s + dppf<DPP_ROR4>(s);
            s = s + dppf<DPP_ROR8>(s);
            const float lse = fmaf(__log2f(s), 0.69314718056f, m);

            outp[(size_t)t * (BB * NTAG)] = lgq - lse;

            xcA = xnA; xcB = xnB;
        }
    }
}

extern "C" void kernel_launch(void* const* d_in, const int* in_sizes, int n_in,
                              void* d_out, int out_size, void* d_ws, size_t ws_size,
                              hipStream_t stream) {
    const float* x        = (const float*)d_in[0];
    const float* w_gates  = (const float*)d_in[1];
    const float* b_gates  = (const float*)d_in[2];
    const float* rx_theta = (const float*)d_in[3];
    const float* w_tag    = (const float*)d_in[4];
    const float* b_tag    = (const float*)d_in[5];
    float* out = (float*)d_out;

    qlstm_fused<<<BB / 4, 64, 0, stream>>>(x, w_gates, b_gates, rx_theta,
                                           w_tag, b_tag, out);
}

// Round 3
// 176.114 us; speedup vs baseline: 1.6639x; 1.1963x over previous
//
#include <hip/hip_runtime.h>

// Problem constants (fixed by reference).
#define TT   512
#define BB   2048
#define NTAG 16
#define CH   8              // timesteps staged per chunk
#define NCH  (TT / CH)      // 64 chunks
#define BBN  (BB * NTAG)

// ---------- DPP helpers ----------
#define DPP_XOR1  0xB1    // quad_perm [1,0,3,2] : lane ^ 1
#define DPP_XOR2  0x4E    // quad_perm [2,3,0,1] : lane ^ 2
#define DPP_XOR3  0x1B    // quad_perm [3,2,1,0] : lane ^ 3
#define DPP_ROR4  0x124   // gate g+3  (verified direction in round 2)
#define DPP_ROR8  0x128   // gate g+2
#define DPP_ROR12 0x12C   // gate g+1

template<int CTRL>
__device__ __forceinline__ float dppf(float v) {
    int r = __builtin_amdgcn_update_dpp(0, __builtin_bit_cast(int, v),
                                        CTRL, 0xF, 0xF, true);
    return __builtin_bit_cast(float, r);
}

// Fused: recurrent scan + tag projection + log_softmax.
// 128 threads = 2 independent waves (forced onto 2 different SIMDs of one CU).
// Per wave: 4 batch elems; lane = e*16 + g*4 + k.
__global__ __launch_bounds__(128) void qlstm_fused(
    const float* __restrict__ x,        // (T,B,8)
    const float* __restrict__ w_gates,  // (4,4,12)
    const float* __restrict__ b_gates,  // (4,4)
    const float* __restrict__ rx_theta, // (4,4)
    const float* __restrict__ w_tag,    // (16,4)
    const float* __restrict__ b_tag,    // (16,)
    float* __restrict__ out)            // (T,B,16)
{
    __shared__ float4 lds4[2][2][CH][8];   // [wave][buf][step][slot]

    const int tid = threadIdx.x;
    const int wv  = tid >> 6;
    const int l   = tid & 63;
    const int e   = l >> 4;
    const int g   = (l >> 2) & 3;
    const int k   = l & 3;
    const int b0  = blockIdx.x * 8 + wv * 4;

    // All angle weights pre-scaled by 1/(2pi): v_cos takes revolutions.
    const float IV = 0.15915494309189535f;
    const float* wrow = w_gates + (g * 4 + k) * 12;
    const float wx0 = wrow[0] * IV, wx1 = wrow[1] * IV, wx2 = wrow[2] * IV,
                wx3 = wrow[3] * IV, wx4 = wrow[4] * IV, wx5 = wrow[5] * IV,
                wx6 = wrow[6] * IV, wx7 = wrow[7] * IV;
    const float wh0 = wrow[8 + (k ^ 0)] * IV;
    const float wh1 = wrow[8 + (k ^ 1)] * IV;
    const float wh2 = wrow[8 + (k ^ 2)] * IV;
    const float wh3 = wrow[8 + (k ^ 3)] * IV;
    const float bias = (b_gates[g * 4 + k] + rx_theta[g * 4 + k]) * IV;

    const int tag = g * 4 + k;              // lane owns one output tag
    const float wt0 = w_tag[tag * 4 + (k ^ 0)];
    const float wt1 = w_tag[tag * 4 + (k ^ 1)];
    const float wt2 = w_tag[tag * 4 + (k ^ 2)];
    const float wt3 = w_tag[tag * 4 + (k ^ 3)];
    const float bt  = b_tag[tag];

    const float L2E = 1.44269504088896f;
    const float LN2 = 0.69314718056f;
    // Branchless activation: gate 2 -> tanh, else sigmoid.
    const float sA = (g == 2) ? (2.0f * L2E) : (-L2E);
    const float aA = (g == 2) ? -2.0f : 1.0f;
    const float bA = (g == 2) ?  1.0f : 0.0f;
    const bool k0 = (k == 0), k1 = (k == 1), k2 = (k == 2);
    const bool g0 = (g == 0), g2 = (g == 2), glo = (g < 2);

    // x staging: lane covers step (l>>3) of each chunk, 16B slot (l&7).
    const float* xlane = x + (size_t)(l >> 3) * (BB * 8)
                           + (size_t)b0 * 8 + (l & 7) * 4;
    const size_t CHOFF = (size_t)CH * BB * 8;
    float4* ldsw = (float4*)&lds4[wv][0][0][0];

    // ---- prologue: chunk0 -> buf0, chunk1 -> regs ----
    float4 reg = *(const float4*)(xlane);
    ldsw[l] = reg;
    reg = *(const float4*)(xlane + CHOFF);

    float4 xcA = lds4[wv][0][0][2 * e];
    float4 xcB = lds4[wv][0][0][2 * e + 1];

    float h = 0.f, c = 0.f, h1 = 0.f, h2 = 0.f, h3 = 0.f;
    float* outp = out + (size_t)b0 * NTAG + l;   // 64 lanes = 256B per t

    for (int cc = 0; cc < NCH; ++cc) {
        const int cur = cc & 1;
        ldsw[(cur ^ 1) * 64 + l] = reg;          // stage chunk cc+1
        const int cn = (cc + 2 < NCH) ? cc + 2 : NCH - 1;
        reg = *(const float4*)(xlane + (size_t)cn * CHOFF);  // issue chunk cc+2

        #pragma unroll
        for (int i = 0; i < CH; ++i) {
            // prefetch x for next step (off-chain)
            const int nb = (i == CH - 1) ? (cur ^ 1) : cur;
            const int ns = (i + 1) & (CH - 1);
            const float4 xnA = lds4[wv][nb][ns][2 * e];
            const float4 xnB = lds4[wv][nb][ns][2 * e + 1];

            const float accx = bias
                + xcA.x * wx0 + xcA.y * wx1 + xcA.z * wx2 + xcA.w * wx3
                + xcB.x * wx4 + xcB.y * wx5 + xcB.z * wx6 + xcB.w * wx7;
            // ang in revolutions; balanced tree off h
            const float p01 = fmaf(h,  wh0, h1 * wh1);
            const float p23 = fmaf(h2, wh2, h3 * wh3);
            const float ang = (accx + p01) + p23;

            const float C = __builtin_amdgcn_cosf(ang);   // cos(2*pi*ang)
            // wire-product butterfly: k0:C1C2C3, k1:C0C1, k2:C0C1C2, k3:all
            const float cx1  = dppf<DPP_XOR1>(C);
            const float pp   = C * cx1;
            const float ppx2 = dppf<DPP_XOR2>(pp);
            const float Asel = k0 ? cx1 : (k2 ? C : pp);  // depth-2 tree
            const float Bsel = k1 ? 1.0f : ppx2;
            const float q = Asel * Bsel;

            const float eq  = __builtin_amdgcn_exp2f(q * sA);
            const float r   = __builtin_amdgcn_rcpf(1.0f + eq);
            const float act = fmaf(r, aA, bA);

            // gate gather via DPP rotations + depth-2 select trees
            const float rA = dppf<DPP_ROR12>(act);  // gate g+1
            const float rB = dppf<DPP_ROR8>(act);   // gate g+2
            const float rC = dppf<DPP_ROR4>(act);   // gate g+3
            const float vf = glo ? (g0 ? act : rC) : (g2 ? rB : rA);
            const float vi = glo ? (g0 ? rA : act) : (g2 ? rC : rB);
            const float vgt = glo ? (g0 ? rB : rA) : (g2 ? act : rC);
            const float vo = glo ? (g0 ? rC : rB) : (g2 ? rA : act);

            c = fmaf(vf, c, vi * vgt);
            const float e2c = __builtin_amdgcn_exp2f(c * (2.0f * L2E));
            const float tc  = fmaf(__builtin_amdgcn_rcpf(1.0f + e2c), -2.0f, 1.0f);
            h = vo * tc;

            // h gather: single DPP level (feeds next h-dot and the logits)
            h1 = dppf<DPP_XOR1>(h);
            h2 = dppf<DPP_XOR2>(h);
            h3 = dppf<DPP_XOR3>(h);

            // ---- fused projection + log_softmax (off the recurrence chain) ----
            // logits bounded (|h|<1) -> no max-shift needed
            const float lgq = fmaf(h, wt0, fmaf(h1, wt1, fmaf(h2, wt2,
                                 fmaf(h3, wt3, bt))));
            const float ex = __builtin_amdgcn_exp2f(lgq * L2E);
            float s = ex + dppf<DPP_XOR1>(ex);
            s = s + dppf<DPP_XOR2>(s);
            s = s + dppf<DPP_ROR4>(s);
            s = s + dppf<DPP_ROR8>(s);
            const float lse = __builtin_amdgcn_logf(s) * LN2;

            *outp = lgq - lse;
            outp += BBN;

            xcA = xnA; xcB = xnB;
        }
    }
}

extern "C" void kernel_launch(void* const* d_in, const int* in_sizes, int n_in,
                              void* d_out, int out_size, void* d_ws, size_t ws_size,
                              hipStream_t stream) {
    const float* x        = (const float*)d_in[0];
    const float* w_gates  = (const float*)d_in[1];
    const float* b_gates  = (const float*)d_in[2];
    const float* rx_theta = (const float*)d_in[3];
    const float* w_tag    = (const float*)d_in[4];
    const float* b_tag    = (const float*)d_in[5];
    float* out = (float*)d_out;

    qlstm_fused<<<BB / 8, 128, 0, stream>>>(x, w_gates, b_gates, rx_theta,
                                            w_tag, b_tag, out);
}

// Round 4
// 171.305 us; speedup vs baseline: 1.7106x; 1.0281x over previous
//
#include <hip/hip_runtime.h>

// Problem constants (fixed by reference).
#define TT   512
#define BB   2048
#define NTAG 16
#define CH   8              // timesteps staged per chunk
#define NCH  (TT / CH)      // 64 chunks
#define BBN  (BB * NTAG)

// ---------- DPP helpers ----------
#define DPP_XOR1  0xB1    // quad_perm [1,0,3,2] : lane ^ 1
#define DPP_XOR2  0x4E    // quad_perm [2,3,0,1] : lane ^ 2
#define DPP_XOR3  0x1B    // quad_perm [3,2,1,0] : lane ^ 3
#define DPP_ROR4  0x124   // gate g+3  (direction verified round 2)
#define DPP_ROR8  0x128   // gate g+2
#define DPP_ROR12 0x12C   // gate g+1

template<int CTRL>
__device__ __forceinline__ float dppf(float v) {
    int r = __builtin_amdgcn_update_dpp(0, __builtin_bit_cast(int, v),
                                        CTRL, 0xF, 0xF, true);
    return __builtin_bit_cast(float, r);
}

// Fused: recurrent scan + tag projection + log_softmax.
// 128 threads = 2 independent waves on 2 SIMDs of one CU.
// Per wave: 4 batch elems; lane = e*16 + g*4 + k.
__global__ __launch_bounds__(128) void qlstm_fused(
    const float* __restrict__ x,        // (T,B,8)
    const float* __restrict__ w_gates,  // (4,4,12)
    const float* __restrict__ b_gates,  // (4,4)
    const float* __restrict__ rx_theta, // (4,4)
    const float* __restrict__ w_tag,    // (16,4)
    const float* __restrict__ b_tag,    // (16,)
    float* __restrict__ out)            // (T,B,16)
{
    __shared__ float4 lds4[2][2][CH][8];   // [wave][buf][step][slot]

    const int tid = threadIdx.x;
    const int wv  = tid >> 6;
    const int l   = tid & 63;
    const int e   = l >> 4;
    const int g   = (l >> 2) & 3;
    const int k   = l & 3;
    const int b0  = blockIdx.x * 8 + wv * 4;

    // All angle weights pre-scaled by 1/(2pi): v_cos takes revolutions.
    const float IV = 0.15915494309189535f;
    const float* wrow = w_gates + (g * 4 + k) * 12;
    const float wx0 = wrow[0] * IV, wx1 = wrow[1] * IV, wx2 = wrow[2] * IV,
                wx3 = wrow[3] * IV, wx4 = wrow[4] * IV, wx5 = wrow[5] * IV,
                wx6 = wrow[6] * IV, wx7 = wrow[7] * IV;
    const float wh0 = wrow[8 + (k ^ 0)] * IV;
    const float wh1 = wrow[8 + (k ^ 1)] * IV;
    const float wh2 = wrow[8 + (k ^ 2)] * IV;
    const float wh3 = wrow[8 + (k ^ 3)] * IV;
    const float bias = (b_gates[g * 4 + k] + rx_theta[g * 4 + k]) * IV;

    const int tag = g * 4 + k;              // lane owns one output tag
    const float wt0 = w_tag[tag * 4 + (k ^ 0)];
    const float wt1 = w_tag[tag * 4 + (k ^ 1)];
    const float wt2 = w_tag[tag * 4 + (k ^ 2)];
    const float wt3 = w_tag[tag * 4 + (k ^ 3)];
    const float bt  = b_tag[tag];

    const float L2E = 1.44269504088896f;
    const float LN2 = 0.69314718056f;

    // Branchless gate activation: odd poly act = bA + x*P(x^2), x in [-1,1].
    // g==2 -> tanh (deg-9 fit, err<=2e-5); else sigmoid (deg-9 Taylor, err~2e-6).
    const bool gt = (g == 2);
    const float bA = gt ? 0.0f : 0.5f;
    const float d0 = gt ? 0.999984f    : 0.25f;
    const float d1 = gt ? -0.332901f   : -0.0208333333f;
    const float d2 = gt ? 0.130238f    : 0.00208333333f;
    const float d3 = gt ? -0.044839f   : -2.10813e-4f;
    const float d4 = gt ? 0.0091125f   : 2.13583e-5f;

    // tanh(c) deg-11 odd poly, |c| <= 2.0703 (proved: f,i<=sigma(1), |g~|<=tanh(1)),
    // fit on [0,2.1], err <= ~6e-4. Uniform across lanes (scalar constants).
    const float u0 = 0.999160f,  u1 = -0.325289f, u2 = 0.112257f;
    const float u3 = -0.028766f, u4 = 0.0043665f, u5 = -0.00028186f;

    const bool k0 = (k == 0), k1 = (k == 1), k3 = (k == 3);
    const bool g0 = (g == 0), g2 = (g == 2), glo = (g < 2);

    // x staging: lane covers step (l>>3) of each chunk, 16B slot (l&7).
    const float* xlane = x + (size_t)(l >> 3) * (BB * 8)
                           + (size_t)b0 * 8 + (l & 7) * 4;
    const size_t CHOFF = (size_t)CH * BB * 8;
    float4* ldsw = (float4*)&lds4[wv][0][0][0];

    // ---- prologue: chunk0 -> buf0, chunk1 -> regs ----
    float4 reg = *(const float4*)(xlane);
    ldsw[l] = reg;
    reg = *(const float4*)(xlane + CHOFF);

    float4 xcA = lds4[wv][0][0][2 * e];
    float4 xcB = lds4[wv][0][0][2 * e + 1];

    float h = 0.f, c = 0.f, h1 = 0.f, h2 = 0.f, h3 = 0.f;
    float* outp = out + (size_t)b0 * NTAG + l;   // 64 lanes = 256B per t

    for (int cc = 0; cc < NCH; ++cc) {
        const int cur = cc & 1;
        ldsw[(cur ^ 1) * 64 + l] = reg;          // stage chunk cc+1
        const int cn = (cc + 2 < NCH) ? cc + 2 : NCH - 1;
        reg = *(const float4*)(xlane + (size_t)cn * CHOFF);  // issue chunk cc+2

        #pragma unroll
        for (int i = 0; i < CH; ++i) {
            // prefetch x for next step (off-chain)
            const int nb = (i == CH - 1) ? (cur ^ 1) : cur;
            const int ns = (i + 1) & (CH - 1);
            const float4 xnA = lds4[wv][nb][ns][2 * e];
            const float4 xnB = lds4[wv][nb][ns][2 * e + 1];

            // off-chain: x-dot + bias (in revolutions)
            const float accx = bias
                + xcA.x * wx0 + xcA.y * wx1 + xcA.z * wx2 + xcA.w * wx3
                + xcB.x * wx4 + xcB.y * wx5 + xcB.z * wx6 + xcB.w * wx7;
            // on-chain: sequential fma string (starts before DPP gather lands)
            float ang = fmaf(h,  wh0, accx);
            ang = fmaf(h1, wh1, ang);
            ang = fmaf(h2, wh2, ang);
            ang = fmaf(h3, wh3, ang);

            const float C = __builtin_amdgcn_cosf(ang);   // cos(2*pi*ang)
            // wire-product via 3 parallel DPPs:
            // k0: m1*(m2*m3), k1: C*m1, k2: C*(m2*m3), k3: (C*m1)*(m2*m3)
            const float m1 = dppf<DPP_XOR1>(C);
            const float m2 = dppf<DPP_XOR2>(C);
            const float m3 = dppf<DPP_XOR3>(C);
            const float Bp = m2 * m3;
            const float pp = C * m1;
            const float X  = k0 ? m1 : (k3 ? pp : C);
            const float Y  = k1 ? m1 : Bp;
            const float q  = X * Y;                       // q in [-1,1]

            // gate activation: odd poly, Estrin
            const float y  = q * q;
            const float y2 = y * y;
            const float tA = fmaf(y, d1, d0);
            const float tB = fmaf(y, d3, d2);
            const float tC = fmaf(y2, d4, tB);
            const float P  = fmaf(y2, tC, tA);
            const float act = fmaf(q, P, bA);

            // gate gather via DPP rotations + depth-2 select trees
            const float rA = dppf<DPP_ROR12>(act);  // gate g+1
            const float rB = dppf<DPP_ROR8>(act);   // gate g+2
            const float rC = dppf<DPP_ROR4>(act);   // gate g+3
            const float vf  = glo ? (g0 ? act : rC) : (g2 ? rB : rA);
            const float vi  = glo ? (g0 ? rA : act) : (g2 ? rC : rB);
            const float vgt = glo ? (g0 ? rB : rA) : (g2 ? act : rC);
            const float vo  = glo ? (g0 ? rC : rB) : (g2 ? rA : act);

            c = fmaf(vf, c, vi * vgt);

            // tanh(c) deg-11 odd poly (Estrin); h = (vo*c)*P(c^2)
            const float cy  = c * c;
            const float cy2 = cy * cy;
            const float sA_ = fmaf(cy, u1, u0);
            const float sB_ = fmaf(cy, u3, u2);
            const float sC_ = fmaf(cy, u5, u4);
            const float sD_ = fmaf(cy2, sC_, sB_);
            const float Pc  = fmaf(cy2, sD_, sA_);
            const float voc = vo * c;
            h = Pc * voc;

            // h gather: single DPP level (feeds next h-dot and the logits)
            h1 = dppf<DPP_XOR1>(h);
            h2 = dppf<DPP_XOR2>(h);
            h3 = dppf<DPP_XOR3>(h);

            // ---- fused projection + log_softmax (off the recurrence chain) ----
            // |h| < 0.71 -> logits bounded, no max-shift needed
            const float lgq = fmaf(h, wt0, fmaf(h1, wt1, fmaf(h2, wt2,
                                 fmaf(h3, wt3, bt))));
            const float ex = __builtin_amdgcn_exp2f(lgq * L2E);
            float s = ex + dppf<DPP_XOR1>(ex);
            s = s + dppf<DPP_XOR2>(s);
            s = s + dppf<DPP_ROR4>(s);
            s = s + dppf<DPP_ROR8>(s);
            const float lse = __builtin_amdgcn_logf(s) * LN2;

            *outp = lgq - lse;
            outp += BBN;

            xcA = xnA; xcB = xnB;
        }
    }
}

extern "C" void kernel_launch(void* const* d_in, const int* in_sizes, int n_in,
                              void* d_out, int out_size, void* d_ws, size_t ws_size,
                              hipStream_t stream) {
    const float* x        = (const float*)d_in[0];
    const float* w_gates  = (const float*)d_in[1];
    const float* b_gates  = (const float*)d_in[2];
    const float* rx_theta = (const float*)d_in[3];
    const float* w_tag    = (const float*)d_in[4];
    const float* b_tag    = (const float*)d_in[5];
    float* out = (float*)d_out;

    qlstm_fused<<<BB / 8, 128, 0, stream>>>(x, w_gates, b_gates, rx_theta,
                                            w_tag, b_tag, out);
}

// Round 5
// 164.289 us; speedup vs baseline: 1.7837x; 1.0427x over previous
//
#include <hip/hip_runtime.h>

// Problem constants (fixed by reference).
#define TT   512
#define BB   2048
#define NTAG 16
#define CH   8              // timesteps staged per chunk
#define NCH  (TT / CH)      // 64 chunks
#define BBN  (BB * NTAG)

typedef float v2f __attribute__((ext_vector_type(2)));

// ---------- DPP helpers ----------
#define DPP_XOR1  0xB1    // quad_perm [1,0,3,2] : lane ^ 1
#define DPP_XOR2  0x4E    // quad_perm [2,3,0,1] : lane ^ 2
#define DPP_XOR3  0x1B    // quad_perm [3,2,1,0] : lane ^ 3
#define DPP_ROR4  0x124   // src gate g+3 == g-1 (verified round 2)
#define DPP_ROR8  0x128   // src gate g+2
#define DPP_ROR12 0x12C   // src gate g+1

template<int CTRL>
__device__ __forceinline__ float dppf(float v) {
    int r = __builtin_amdgcn_update_dpp(0, __builtin_bit_cast(int, v),
                                        CTRL, 0xF, 0xF, true);
    return __builtin_bit_cast(float, r);
}

// Fused: recurrent scan + tag projection + log_softmax.
// 128 threads = 2 independent waves on 2 SIMDs of one CU.
// Per wave: 4 batch elems; lane = e*16 + g*4 + k.
__global__ __launch_bounds__(128) void qlstm_fused(
    const float* __restrict__ x,        // (T,B,8)
    const float* __restrict__ w_gates,  // (4,4,12)
    const float* __restrict__ b_gates,  // (4,4)
    const float* __restrict__ rx_theta, // (4,4)
    const float* __restrict__ w_tag,    // (16,4)
    const float* __restrict__ b_tag,    // (16,)
    float* __restrict__ out)            // (T,B,16)
{
    __shared__ float4 lds4[2][2][CH][8];   // [wave][buf][step][slot]

    const int tid = threadIdx.x;
    const int wv  = tid >> 6;
    const int l   = tid & 63;
    const int e   = l >> 4;
    const int g   = (l >> 2) & 3;
    const int k   = l & 3;
    const int b0  = blockIdx.x * 8 + wv * 4;

    // All angle weights pre-scaled by 1/(2pi): v_cos takes revolutions.
    const float IV = 0.15915494309189535f;
    const float* wrow = w_gates + (g * 4 + k) * 12;
    // packed x-weights (pairs match ds_read_b128 register adjacency)
    const v2f wp0 = { wrow[0] * IV, wrow[1] * IV };
    const v2f wp1 = { wrow[2] * IV, wrow[3] * IV };
    const v2f wp2 = { wrow[4] * IV, wrow[5] * IV };
    const v2f wp3 = { wrow[6] * IV, wrow[7] * IV };
    const float wh0 = wrow[8 + (k ^ 0)] * IV;
    const float wh1 = wrow[8 + (k ^ 1)] * IV;
    const float wh2 = wrow[8 + (k ^ 2)] * IV;
    const float wh3 = wrow[8 + (k ^ 3)] * IV;
    const v2f bp = { (b_gates[g * 4 + k] + rx_theta[g * 4 + k]) * IV, 0.0f };

    const float L2E = 1.44269504088896f;
    const float LN2 = 0.69314718056f;

    // tag weights pre-scaled by log2(e): softmax runs in base 2 throughout
    const int tag = g * 4 + k;              // lane owns one output tag
    const float wt0 = w_tag[tag * 4 + (k ^ 0)] * L2E;
    const float wt1 = w_tag[tag * 4 + (k ^ 1)] * L2E;
    const float wt2 = w_tag[tag * 4 + (k ^ 2)] * L2E;
    const float wt3 = w_tag[tag * 4 + (k ^ 3)] * L2E;
    const float bt  = b_tag[tag] * L2E;

    // Branchless gate activation: odd deg-7 poly act = bA + q*P(q^2), q in [-1,1].
    // g==2 -> tanh (refit, err<=2e-4); else sigmoid (Taylor, err~2e-5).
    const bool gt = (g == 2);
    const float bA = gt ? 0.0f : 0.5f;
    const float d0 = gt ? 0.999904f  : 0.25f;
    const float d1 = gt ? -0.331065f : -0.0208333333f;
    const float d2 = gt ? 0.120472f  : 0.00208333333f;
    const float d3 = gt ? -0.027717f : -2.10813e-4f;

    // tanh(c) deg-11 odd poly, |c| <= 2.0703 (bounded by construction).
    const float u0 = 0.999160f,  u1 = -0.325289f, u2 = 0.112257f;
    const float u3 = -0.028766f, u4 = 0.0043665f, u5 = -0.00028186f;

    const bool k0 = (k == 0), k1 = (k == 1), k3 = (k == 3);
    const bool g0 = (g == 0), g2 = (g == 2), glo = (g < 2);

    // x staging: lane covers step (l>>3) of each chunk, 16B slot (l&7).
    const float* xlane = x + (size_t)(l >> 3) * (BB * 8)
                           + (size_t)b0 * 8 + (l & 7) * 4;
    const size_t CHOFF = (size_t)CH * BB * 8;
    float4* ldsw = (float4*)&lds4[wv][0][0][0];

    // ---- prologue: chunk0 -> buf0, chunk1 -> regs ----
    float4 reg = *(const float4*)(xlane);
    ldsw[l] = reg;
    reg = *(const float4*)(xlane + CHOFF);

    float4 xcA = lds4[wv][0][0][2 * e];
    float4 xcB = lds4[wv][0][0][2 * e + 1];

    float h = 0.f, c = 0.f, h1 = 0.f, h2 = 0.f, h3 = 0.f;
    float* outp = out + (size_t)b0 * NTAG + l;   // 64 lanes = 256B per t

    for (int cc = 0; cc < NCH; ++cc) {
        const int cur = cc & 1;
        ldsw[(cur ^ 1) * 64 + l] = reg;          // stage chunk cc+1
        const int cn = (cc + 2 < NCH) ? cc + 2 : NCH - 1;
        reg = *(const float4*)(xlane + (size_t)cn * CHOFF);  // issue chunk cc+2

        #pragma unroll
        for (int i = 0; i < CH; ++i) {
            // prefetch x for next step (off-chain)
            const int nb = (i == CH - 1) ? (cur ^ 1) : cur;
            const int ns = (i + 1) & (CH - 1);
            const float4 xnA = lds4[wv][nb][ns][2 * e];
            const float4 xnB = lds4[wv][nb][ns][2 * e + 1];

            // off-chain: x-dot via packed f32 (falls back to scalar harmlessly)
            const v2f a01 = { xcA.x, xcA.y }, a23 = { xcA.z, xcA.w };
            const v2f a45 = { xcB.x, xcB.y }, a67 = { xcB.z, xcB.w };
            v2f acc = __builtin_elementwise_fma(a01, wp0, bp);
            acc = __builtin_elementwise_fma(a23, wp1, acc);
            acc = __builtin_elementwise_fma(a45, wp2, acc);
            acc = __builtin_elementwise_fma(a67, wp3, acc);
            const float accx = acc.x + acc.y;

            // on-chain: h-dot as sequential fma string
            float ang = fmaf(h,  wh0, accx);
            ang = fmaf(h1, wh1, ang);
            ang = fmaf(h2, wh2, ang);
            ang = fmaf(h3, wh3, ang);

            const float C = __builtin_amdgcn_cosf(ang);   // cos(2*pi*ang)
            // wire-product via 3 parallel DPPs:
            // k0: m1*(m2*m3), k1: C*m1, k2: C*(m2*m3), k3: (C*m1)*(m2*m3)
            const float m1 = dppf<DPP_XOR1>(C);
            const float m2 = dppf<DPP_XOR2>(C);
            const float m3 = dppf<DPP_XOR3>(C);
            const float Bp = m2 * m3;
            const float pp = C * m1;
            const float X  = k0 ? m1 : (k3 ? pp : C);
            const float Y  = k1 ? m1 : Bp;
            const float q  = X * Y;                       // q in [-1,1]

            // gate activation: odd deg-7 poly (valid on ALL lanes)
            const float y  = q * q;
            const float y2 = y * y;
            const float tA = fmaf(y, d1, d0);
            const float tB = fmaf(y, d3, d2);
            const float P  = fmaf(y2, tB, tA);
            const float act = fmaf(q, P, bA);

            // Role rotation: every lane uses (act, g+1, g+2, g+3) as (f,i,g~,o).
            // Only g==0 lanes produce the TRUE c/h; others carry bounded garbage.
            const float rA = dppf<DPP_ROR12>(act);  // gate g+1
            const float rB = dppf<DPP_ROR8>(act);   // gate g+2
            const float rC = dppf<DPP_ROR4>(act);   // gate g+3
            c = fmaf(act, c, rA * rB);

            // tanh(c) deg-11 odd poly (Estrin); h_raw = (o*c)*P(c^2)
            const float cy  = c * c;
            const float cy2 = cy * cy;
            const float t1  = fmaf(cy, u1, u0);
            const float t2  = fmaf(cy, u3, u2);
            const float t3  = fmaf(cy, u5, u4);
            const float t4  = fmaf(cy2, t3, t2);
            const float Pc  = fmaf(cy2, t4, t1);
            const float voc = rC * c;
            const float h_raw = Pc * voc;

            // redistribute TRUE h (lives on g==0 lanes) to all gate quads
            const float r4  = dppf<DPP_ROR4>(h_raw);   // from lane g-1
            const float r8  = dppf<DPP_ROR8>(h_raw);   // from lane g-2
            const float r12 = dppf<DPP_ROR12>(h_raw);  // from lane g-3
            h = glo ? (g0 ? h_raw : r4) : (g2 ? r8 : r12);

            // h gather within wire-quad (feeds next h-dot and the logits)
            h1 = dppf<DPP_XOR1>(h);
            h2 = dppf<DPP_XOR2>(h);
            h3 = dppf<DPP_XOR3>(h);

            // ---- fused projection + log_softmax, base-2 (off the chain) ----
            const float lgq = fmaf(h, wt0, fmaf(h1, wt1, fmaf(h2, wt2,
                                 fmaf(h3, wt3, bt))));        // log2-scaled logit
            const float ex = __builtin_amdgcn_exp2f(lgq);
            float s = ex + dppf<DPP_XOR1>(ex);
            s = s + dppf<DPP_XOR2>(s);
            s = s + dppf<DPP_ROR4>(s);
            s = s + dppf<DPP_ROR8>(s);
            const float l2s = __builtin_amdgcn_logf(s);       // log2(s)

            *outp = (lgq - l2s) * LN2;
            outp += BBN;

            xcA = xnA; xcB = xnB;
        }
    }
}

extern "C" void kernel_launch(void* const* d_in, const int* in_sizes, int n_in,
                              void* d_out, int out_size, void* d_ws, size_t ws_size,
                              hipStream_t stream) {
    const float* x        = (const float*)d_in[0];
    const float* w_gates  = (const float*)d_in[1];
    const float* b_gates  = (const float*)d_in[2];
    const float* rx_theta = (const float*)d_in[3];
    const float* w_tag    = (const float*)d_in[4];
    const float* b_tag    = (const float*)d_in[5];
    float* out = (float*)d_out;

    qlstm_fused<<<BB / 8, 128, 0, stream>>>(x, w_gates, b_gates, rx_theta,
                                            w_tag, b_tag, out);
}